// Round 3
// baseline (4016.389 us; speedup 1.0000x reference)
//
#include <hip/hip_runtime.h>
#include <math.h>

#define D_MODEL  4096
#define D_HIDDEN 32768
#define BATCH    2048
#define KSEL     128
#define NDEAD    2048

typedef short s16x8 __attribute__((ext_vector_type(8)));
typedef float f32x4 __attribute__((ext_vector_type(4)));

// -------------------- helpers --------------------
__device__ __forceinline__ unsigned int fkey(float f) {
    unsigned int u = __float_as_uint(f);
    return (u & 0x80000000u) ? ~u : (u | 0x80000000u);
}
__device__ __forceinline__ float unfkey(unsigned int k) {
    unsigned int u = (k & 0x80000000u) ? (k & 0x7FFFFFFFu) : ~k;
    return __uint_as_float(u);
}
__device__ __forceinline__ unsigned short f2bf(float f) {  // RTNE
    unsigned int u = __float_as_uint(f);
    u += 0x7FFFu + ((u >> 16) & 1u);
    return (unsigned short)(u >> 16);
}
__device__ __forceinline__ float bf2f(unsigned short h) {
    return __uint_as_float(((unsigned int)h) << 16);
}
__device__ __forceinline__ void async_copy16(void* lds_dst, const void* gsrc) {
    __builtin_amdgcn_global_load_lds(
        (const __attribute__((address_space(1))) unsigned int*)gsrc,
        (__attribute__((address_space(3))) unsigned int*)lds_dst,
        16, 0, 0);
}

// -------------------- LayerNorm (fp64 stats) --------------------
__global__ __launch_bounds__(256) void ln_kernel(const float* __restrict__ x,
        double* __restrict__ mu, double* __restrict__ stdv, double* __restrict__ sinv)
{
    const int row = blockIdx.x;
    const int tid = threadIdx.x;
    const float* xr = x + (size_t)row * D_MODEL;
    float xv[16];
#pragma unroll
    for (int i = 0; i < 16; ++i) xv[i] = xr[tid + 256 * i];
    double s = 0.0;
#pragma unroll
    for (int i = 0; i < 16; ++i) s += (double)xv[i];
    __shared__ double red[4];
    __shared__ double sh_mu;
    const int lane = tid & 63, wid = tid >> 6;
#pragma unroll
    for (int off = 32; off > 0; off >>= 1) s += __shfl_down(s, off, 64);
    if (lane == 0) red[wid] = s;
    __syncthreads();
    if (tid == 0) sh_mu = (red[0] + red[1] + red[2] + red[3]) / (double)D_MODEL;
    __syncthreads();
    const double m = sh_mu;
    double s2 = 0.0;
#pragma unroll
    for (int i = 0; i < 16; ++i) { double d = (double)xv[i] - m; s2 += d * d; }
#pragma unroll
    for (int off = 32; off > 0; off >>= 1) s2 += __shfl_down(s2, off, 64);
    __syncthreads();
    if (lane == 0) red[wid] = s2;
    __syncthreads();
    if (tid == 0) {
        double var = (red[0] + red[1] + red[2] + red[3]) / (double)(D_MODEL - 1);
        double sd = sqrt(var);
        mu[row] = m;
        stdv[row] = sd;
        sinv[row] = 1.0 / (sd + 1e-5);
    }
}

// -------------------- dead-mask scan --------------------
__global__ void dead_scan_kernel(const unsigned char* __restrict__ mask8,
                                 int* __restrict__ dead_idx, int* __restrict__ dead_cnt,
                                 const int* __restrict__ num_dead_in, float* __restrict__ out_last)
{
    const int lane = threadIdx.x; // 64 threads, one wave
    int c = 0;
    for (int j = lane; j < D_HIDDEN; j += 64) c += (mask8[j] != 0);
#pragma unroll
    for (int off = 32; off > 0; off >>= 1) c += __shfl_down(c, off, 64);
    const int total_u8 = __shfl(c, 0, 64);
    const bool u8mode = (total_u8 == NDEAD);
    const int* mask32 = (const int*)mask8;
    int cnt = 0;
    for (int base = 0; base < D_HIDDEN; base += 64) {
        const int j = base + lane;
        const bool d = u8mode ? (mask8[j] != 0) : (mask32[j] != 0);
        const unsigned long long b = __ballot(d);
        const int pre = __popcll(b & ((1ull << lane) - 1ull));
        if (d && (cnt + pre) < NDEAD) dead_idx[cnt + pre] = j;
        cnt += __popcll(b);
    }
    const int cc = cnt > NDEAD ? NDEAD : cnt;
    if (lane == 0) {
        *dead_cnt = cc;
        *out_last = (float)(*num_dead_in);
    }
    for (int t = cc + lane; t < NDEAD; t += 64) dead_idx[t] = 0;
}

// -------------------- A split: xc -> hi/mid bf16 planes --------------------
__global__ __launch_bounds__(256) void asplit_kernel(
    const float* __restrict__ x, const double* __restrict__ mu, const double* __restrict__ sinv,
    const float* __restrict__ b_pre,
    unsigned short* __restrict__ Ahp, unsigned short* __restrict__ Amp)
{
    const int row = blockIdx.x, tid = threadIdx.x;
    const double m = mu[row], si = sinv[row];
    const float* xr = x + (size_t)row * D_MODEL;
#pragma unroll
    for (int i = 0; i < 4; ++i) {
        const int j = (i * 256 + tid) * 4;
        const float4 xv = *(const float4*)(xr + j);
        const float4 bp = *(const float4*)(b_pre + j);
        float v[4];
        v[0] = (float)(((double)xv.x - m) * si) - bp.x;
        v[1] = (float)(((double)xv.y - m) * si) - bp.y;
        v[2] = (float)(((double)xv.z - m) * si) - bp.z;
        v[3] = (float)(((double)xv.w - m) * si) - bp.w;
        unsigned short h[4], md[4];
#pragma unroll
        for (int e = 0; e < 4; ++e) {
            h[e] = f2bf(v[e]);
            md[e] = f2bf(v[e] - bf2f(h[e]));
        }
        uint2 hw, mw;
        hw.x = (unsigned)h[0] | ((unsigned)h[1] << 16);
        hw.y = (unsigned)h[2] | ((unsigned)h[3] << 16);
        mw.x = (unsigned)md[0] | ((unsigned)md[1] << 16);
        mw.y = (unsigned)md[2] | ((unsigned)md[3] << 16);
        *(uint2*)(Ahp + (size_t)row * D_MODEL + j) = hw;
        *(uint2*)(Amp + (size_t)row * D_MODEL + j) = mw;
    }
}

// -------------------- B split+transpose: w_enc[k][n] -> Bh/Bm[n][k] --------------------
__global__ __launch_bounds__(256) void bsplit_kernel(
    const float* __restrict__ w_enc,
    unsigned short* __restrict__ Bhp, unsigned short* __restrict__ Bmp)
{
    __shared__ float t[32][33];
    const int bk = blockIdx.x * 32;
    const int bn = blockIdx.y * 32;
    const int tid = threadIdx.x;
    const int lr = tid >> 3, lc4 = (tid & 7) * 4;
    const float4 v = *(const float4*)(w_enc + (size_t)(bk + lr) * D_HIDDEN + bn + lc4);
    t[lr][lc4 + 0] = v.x; t[lr][lc4 + 1] = v.y; t[lr][lc4 + 2] = v.z; t[lr][lc4 + 3] = v.w;
    __syncthreads();
    float o[4];
#pragma unroll
    for (int j = 0; j < 4; ++j) o[j] = t[lc4 + j][lr];
    unsigned short h[4], md[4];
#pragma unroll
    for (int e = 0; e < 4; ++e) {
        h[e] = f2bf(o[e]);
        md[e] = f2bf(o[e] - bf2f(h[e]));
    }
    uint2 hw, mw;
    hw.x = (unsigned)h[0] | ((unsigned)h[1] << 16);
    hw.y = (unsigned)h[2] | ((unsigned)h[3] << 16);
    mw.x = (unsigned)md[0] | ((unsigned)md[1] << 16);
    mw.y = (unsigned)md[2] | ((unsigned)md[3] << 16);
    *(uint2*)(Bhp + (size_t)(bn + lr) * D_MODEL + bk + lc4) = hw;
    *(uint2*)(Bmp + (size_t)(bn + lr) * D_MODEL + bk + lc4) = mw;
}

// -------------------- unified split-bf16 3-product MFMA GEMM --------------------
// A[m][k] hi/mid, B[n][k] hi/mid (transposed layout), out[m][n].
// EPI=0: out = acc + bias_n[col]          (encoder -> p32)
// EPI=1: out = (acc + bias_n[col])*std[m] + mu[m]   (aux -> out1)
template<int EPI>
__global__ __launch_bounds__(256) void mm3_kernel(
    const unsigned short* __restrict__ Ah, const unsigned short* __restrict__ Am,
    const unsigned short* __restrict__ Bh, const unsigned short* __restrict__ Bm,
    const int kdim, const float* __restrict__ bias_n,
    const double* __restrict__ muv, const double* __restrict__ stdvv,
    float* __restrict__ outp, const long ostride)
{
    __shared__ unsigned short lds[4 * 128 * 32];  // planes: Ah, Am, Bh, Bm; [row][32] linear
    const int tid = threadIdx.x;
    const int lane = tid & 63, wid = tid >> 6;
    const int m0 = blockIdx.x * 128;
    const int n0 = blockIdx.y * 128;
    const int wm = (wid >> 1) * 64, wn = (wid & 1) * 64;
    const int fr = lane & 15, kq = lane >> 4;

    f32x4 acc[4][4];
#pragma unroll
    for (int i = 0; i < 4; ++i)
#pragma unroll
        for (int j = 0; j < 4; ++j) acc[i][j] = (f32x4){0.f, 0.f, 0.f, 0.f};

    // wave w stages plane w via global_load_lds (linear LDS, m97 pattern)
    const unsigned short* gp = (wid == 0) ? Ah : (wid == 1) ? Am : (wid == 2) ? Bh : Bm;
    const int t0 = (wid < 2) ? m0 : n0;
    const unsigned short* src0 = gp + (size_t)(t0 + (lane >> 2)) * kdim + (lane & 3) * 8;

    for (int k0 = 0; k0 < kdim; k0 += 32) {
#pragma unroll
        for (int seg = 0; seg < 8; ++seg) {
            async_copy16(lds + wid * 4096 + seg * 512, src0 + k0 + (size_t)seg * 16 * kdim);
        }
        __syncthreads();

        s16x8 ah[4], am[4], bh[4], bm[4];
#pragma unroll
        for (int i = 0; i < 4; ++i) {
            ah[i] = *(const s16x8*)(lds + 0 * 4096 + (wm + i * 16 + fr) * 32 + kq * 8);
            am[i] = *(const s16x8*)(lds + 1 * 4096 + (wm + i * 16 + fr) * 32 + kq * 8);
            bh[i] = *(const s16x8*)(lds + 2 * 4096 + (wn + i * 16 + fr) * 32 + kq * 8);
            bm[i] = *(const s16x8*)(lds + 3 * 4096 + (wn + i * 16 + fr) * 32 + kq * 8);
        }
#pragma unroll
        for (int mi = 0; mi < 4; ++mi)
#pragma unroll
            for (int ni = 0; ni < 4; ++ni) {
                acc[mi][ni] = __builtin_amdgcn_mfma_f32_16x16x32_bf16(ah[mi], bh[ni], acc[mi][ni], 0, 0, 0);
                acc[mi][ni] = __builtin_amdgcn_mfma_f32_16x16x32_bf16(ah[mi], bm[ni], acc[mi][ni], 0, 0, 0);
                acc[mi][ni] = __builtin_amdgcn_mfma_f32_16x16x32_bf16(am[mi], bh[ni], acc[mi][ni], 0, 0, 0);
            }
        __syncthreads();
    }
#pragma unroll
    for (int ni = 0; ni < 4; ++ni) {
        const int col = n0 + wn + ni * 16 + fr;
        const float be = bias_n[col];
#pragma unroll
        for (int mi = 0; mi < 4; ++mi) {
            const int rb = m0 + wm + mi * 16 + kq * 4;
            if (EPI == 0) {
                float* dst = outp + (size_t)rb * ostride + col;
                dst[0]                      = acc[mi][ni][0] + be;
                dst[(size_t)ostride]        = acc[mi][ni][1] + be;
                dst[2 * (size_t)ostride]    = acc[mi][ni][2] + be;
                dst[3 * (size_t)ostride]    = acc[mi][ni][3] + be;
            } else {
#pragma unroll
                for (int r = 0; r < 4; ++r) {
                    const int m = rb + r;
                    const float st = (float)stdvv[m];
                    const float mm = (float)muv[m];
                    outp[(size_t)m * ostride + col] = (acc[mi][ni][r] + be) * st + mm;
                }
            }
        }
    }
}

// -------------------- per-row top-128: LDS-staged radix + band-exact refinement --------------------
__global__ __launch_bounds__(256) void topk_kernel(
    const float* __restrict__ p32,
    const float* __restrict__ x, const double* __restrict__ mu, const double* __restrict__ sinv,
    const float* __restrict__ b_pre, const float* __restrict__ w_enc, const float* __restrict__ b_enc,
    int* __restrict__ topk_idx, float* __restrict__ topk_val)
{
    const int row = blockIdx.x;
    const int tid = threadIdx.x;
    const float* pr = p32 + (size_t)row * D_HIDDEN;

    __shared__ float prow[D_HIDDEN];          // 128 KB row stage
    __shared__ unsigned int hist[256];
    __shared__ unsigned int sh_prefix, sh_remaining;
    __shared__ int sh_sel, sh_tiecnt;
    __shared__ int tie_idx[128];
    __shared__ double tie_val[128];
    __shared__ unsigned char tie_sel[128];
    __shared__ double red[256];

    // stage row into LDS (single global read of p32)
#pragma unroll
    for (int i = 0; i < 32; ++i) {
        const int j = (i * 256 + tid) * 4;
        *(float4*)(prow + j) = *(const float4*)(pr + j);
    }
    if (tid == 0) { sh_prefix = 0u; sh_remaining = KSEL; }
    __syncthreads();

    for (int p = 0; p < 4; ++p) {
        const int shift = 24 - 8 * p;
        hist[tid] = 0u;
        __syncthreads();
        const unsigned int prefix = sh_prefix;
        const unsigned int maskhi = (p == 0) ? 0u : (0xFFFFFFFFu << (shift + 8));
        for (int j = tid; j < D_HIDDEN; j += 256) {
            const unsigned int key = fkey(prow[j]);
            if (((key ^ prefix) & maskhi) == 0u)
                atomicAdd(&hist[(key >> shift) & 255u], 1u);
        }
        __syncthreads();
        if (tid == 0) {
            unsigned int cum = 0, rem = sh_remaining;
            const unsigned int pf = sh_prefix;
            for (int d = 255; d >= 0; --d) {
                const unsigned int c = hist[d];
                if (cum + c >= rem) {
                    sh_prefix = pf | ((unsigned int)d << shift);
                    sh_remaining = rem - cum;
                    break;
                }
                cum += c;
            }
        }
        __syncthreads();
    }
    const float c = unfkey(sh_prefix);
    const float dlt = 2e-4f;   // > 2x the split-bf16 GEMM error bound (~6e-5)
    const float hiT = c + dlt, loT = c - dlt;
    if (tid == 0) { sh_sel = 0; sh_tiecnt = 0; }
    __syncthreads();

    int* oidx = topk_idx + row * KSEL;
    float* oval = topk_val + row * KSEL;
    for (int j = tid; j < D_HIDDEN; j += 256) {
        const float v = prow[j];
        if (v > hiT) {
            const int pos = atomicAdd(&sh_sel, 1);
            oidx[pos] = j;
            oval[pos] = v > 0.f ? v : 0.f;
        } else if (v >= loT) {
            const int t = atomicAdd(&sh_tiecnt, 1);
            if (t < 128) tie_idx[t] = j;
        }
    }
    __syncthreads();
    const int G = sh_sel;
    int T = sh_tiecnt; if (T > 128) T = 128;
    const int R = KSEL - G;  // needed from candidates

    // exact fp64 recompute of all candidates
    const double m_ = mu[row], si = sinv[row];
    const float* xr = x + (size_t)row * D_MODEL;
    for (int t = 0; t < T; ++t) {
        const int col = tie_idx[t];
        double s = 0.0;
        for (int k = tid; k < D_MODEL; k += 256) {
            const double a = ((double)xr[k] - m_) * si - (double)b_pre[k];
            s += a * (double)w_enc[(size_t)k * D_HIDDEN + col];
        }
        red[tid] = s;
        __syncthreads();
        for (int off = 128; off > 0; off >>= 1) {
            if (tid < off) red[tid] += red[tid + off];
            __syncthreads();
        }
        if (tid == 0) tie_val[t] = red[0] + (double)b_enc[col];
        __syncthreads();
    }
    if (tid == 0) {
        for (int t = 0; t < T; ++t) tie_sel[t] = 0;
        const int take = R < T ? R : T;
        for (int r = 0; r < take; ++r) {
            int best = -1;
            for (int t = 0; t < T; ++t) {
                if (tie_sel[t]) continue;
                if (best < 0 || tie_val[t] > tie_val[best] ||
                    (tie_val[t] == tie_val[best] && tie_idx[t] < tie_idx[best])) best = t;
            }
            tie_sel[best] = 1;
            const float ev = (float)tie_val[best];
            oidx[G + r] = tie_idx[best];
            oval[G + r] = ev > 0.f ? ev : 0.f;
        }
        for (int r = take; r < R; ++r) { oidx[G + r] = tie_idx[0]; oval[G + r] = 0.f; }
    }
}

// -------------------- w_dec -> bf16 row-major copy --------------------
__global__ __launch_bounds__(256) void wdec2bf_kernel(
    const float* __restrict__ w_dec, unsigned short* __restrict__ wd16)
{
    const size_t gid = (size_t)blockIdx.x * 256 + threadIdx.x;
    const size_t base = gid * 8;
    const float4 a = *(const float4*)(w_dec + base);
    const float4 b = *(const float4*)(w_dec + base + 4);
    uint4 o;
    o.x = (unsigned)f2bf(a.x) | ((unsigned)f2bf(a.y) << 16);
    o.y = (unsigned)f2bf(a.z) | ((unsigned)f2bf(a.w) << 16);
    o.z = (unsigned)f2bf(b.x) | ((unsigned)f2bf(b.y) << 16);
    o.w = (unsigned)f2bf(b.z) | ((unsigned)f2bf(b.w) << 16);
    *(uint4*)(wd16 + base) = o;
}

// -------------------- sparse decode: recons (bf16 w_dec) --------------------
__global__ __launch_bounds__(256) void decode_kernel(
    const int* __restrict__ topk_idx, const float* __restrict__ topk_val,
    const unsigned short* __restrict__ wd16, const float* __restrict__ b_pre,
    const double* __restrict__ mu, const double* __restrict__ stdv,
    float* __restrict__ out0)
{
    const int row = blockIdx.x;
    const int tid = threadIdx.x;
    __shared__ int sidx[KSEL];
    __shared__ float sval[KSEL];
    if (tid < KSEL) {
        sidx[tid] = topk_idx[row * KSEL + tid];
        sval[tid] = topk_val[row * KSEL + tid];
    }
    __syncthreads();
    float acc[16];
#pragma unroll
    for (int i = 0; i < 16; ++i) acc[i] = 0.f;
    const int dbase = tid * 16;
    for (int k = 0; k < KSEL; ++k) {
        const float v = sval[k];
        if (v == 0.f) continue;
        const uint4* wr = (const uint4*)(wd16 + (size_t)sidx[k] * D_MODEL + dbase);
        const uint4 w0 = wr[0], w1 = wr[1];
        const unsigned int u[8] = {w0.x, w0.y, w0.z, w0.w, w1.x, w1.y, w1.z, w1.w};
#pragma unroll
        for (int i = 0; i < 8; ++i) {
            acc[2 * i]     += v * __uint_as_float(u[i] << 16);
            acc[2 * i + 1] += v * __uint_as_float(u[i] & 0xFFFF0000u);
        }
    }
    const float st = (float)stdv[row];
    const float mm = (float)mu[row];
    float* o = out0 + (size_t)row * D_MODEL + dbase;
#pragma unroll
    for (int i = 0; i < 16; ++i) {
        o[i] = (acc[i] + b_pre[dbase + i]) * st + mm;
    }
}

// -------------------- aux A gather+relu+split: p32 dead cols -> bf16 planes --------------------
__global__ __launch_bounds__(256) void auxg_split_kernel(
    const float* __restrict__ p32, const int* __restrict__ dead_idx,
    const int* __restrict__ dead_cnt,
    unsigned short* __restrict__ Ahd, unsigned short* __restrict__ Amd)
{
    const int r = blockIdx.x;
    const int tid = threadIdx.x;
    const int dc = *dead_cnt;
    for (int c = tid; c < NDEAD; c += 256) {
        float v = 0.f;
        if (c < dc) {
            v = p32[(size_t)r * D_HIDDEN + dead_idx[c]];
            v = v > 0.f ? v : 0.f;
        }
        const unsigned short h = f2bf(v);
        const unsigned short md = f2bf(v - bf2f(h));
        Ahd[(size_t)r * NDEAD + c] = h;
        Amd[(size_t)r * NDEAD + c] = md;
    }
}

// -------------------- aux B gather+transpose+split: w_dec[dead] -> BT planes --------------------
__global__ __launch_bounds__(256) void auxb_split_kernel(
    const float* __restrict__ w_dec, const int* __restrict__ dead_idx,
    unsigned short* __restrict__ Bhd, unsigned short* __restrict__ Bmd)
{
    __shared__ float t[32][33];
    const int k0 = blockIdx.x * 32;
    const int n0 = blockIdx.y * 32;
    const int tid = threadIdx.x;
    const int i = tid >> 3, j4 = (tid & 7) * 4;
    const int srow = dead_idx[k0 + i];
    const float4 v = *(const float4*)(w_dec + (size_t)srow * D_MODEL + n0 + j4);
    t[i][j4 + 0] = v.x; t[i][j4 + 1] = v.y; t[i][j4 + 2] = v.z; t[i][j4 + 3] = v.w;
    __syncthreads();
    // write transposed: row n, cols k
    const int j = tid >> 3, i4 = (tid & 7) * 4;
    unsigned short h[4], md[4];
#pragma unroll
    for (int e = 0; e < 4; ++e) {
        const float vv = t[i4 + e][j];
        h[e] = f2bf(vv);
        md[e] = f2bf(vv - bf2f(h[e]));
    }
    uint2 hw, mw;
    hw.x = (unsigned)h[0] | ((unsigned)h[1] << 16);
    hw.y = (unsigned)h[2] | ((unsigned)h[3] << 16);
    mw.x = (unsigned)md[0] | ((unsigned)md[1] << 16);
    mw.y = (unsigned)md[2] | ((unsigned)md[3] << 16);
    *(uint2*)(Bhd + (size_t)(n0 + j) * NDEAD + k0 + i4) = hw;
    *(uint2*)(Bmd + (size_t)(n0 + j) * NDEAD + k0 + i4) = mw;
}

// -------------------- launch --------------------
extern "C" void kernel_launch(void* const* d_in, const int* in_sizes, int n_in,
                              void* d_out, int out_size, void* d_ws, size_t ws_size,
                              hipStream_t stream)
{
    (void)in_sizes; (void)n_in; (void)out_size; (void)ws_size;
    const float* x      = (const float*)d_in[0];
    const float* w_enc  = (const float*)d_in[1];
    const float* w_dec  = (const float*)d_in[2];
    const float* b_enc  = (const float*)d_in[3];
    const float* b_pre  = (const float*)d_in[4];
    const unsigned char* dead_mask = (const unsigned char*)d_in[5];
    const int* num_dead = (const int*)d_in[6];
    float* out = (float*)d_out;

    char* base = (char*)d_ws;
    char* w = base;
    auto alloc = [&](size_t bytes) -> char* {
        char* p = w;
        w += (bytes + 255) & ~(size_t)255;
        return p;
    };
    float* p32       = (float*)alloc((size_t)BATCH * D_HIDDEN * 4);   // 256 MB
    double* mu       = (double*)alloc((size_t)BATCH * 8);
    double* stdv     = (double*)alloc((size_t)BATCH * 8);
    double* sinv     = (double*)alloc((size_t)BATCH * 8);
    int* topk_idx    = (int*)alloc((size_t)BATCH * KSEL * 4);
    float* topk_val  = (float*)alloc((size_t)BATCH * KSEL * 4);
    int* dead_idx    = (int*)alloc((size_t)NDEAD * 4);
    int* dead_cnt    = (int*)alloc(256);
    unsigned short* Ahp = (unsigned short*)alloc((size_t)BATCH * D_MODEL * 2);    // 16 MB
    unsigned short* Amp = (unsigned short*)alloc((size_t)BATCH * D_MODEL * 2);    // 16 MB
    unsigned short* Bhp = (unsigned short*)alloc((size_t)D_HIDDEN * D_MODEL * 2); // 256 MB
    unsigned short* Bmp = (unsigned short*)alloc((size_t)D_HIDDEN * D_MODEL * 2); // 256 MB

    // aliases into buffers that are dead after the encoder GEMM:
    unsigned short* wd16 = Bhp;                                  // 256 MB bf16 w_dec copy
    unsigned short* Ahd  = Ahp;                                  // 8 MB
    unsigned short* Amd  = Ahp + (size_t)BATCH * NDEAD;          // 8 MB (2nd half of Ahp)
    unsigned short* Bhd  = Amp;                                  // 16 MB (exact fit)
    unsigned short* Bmd  = Bmp;                                  // 16 MB (head of Bmp)

    float* out0 = out;                                   // recons
    float* out1 = out + (size_t)BATCH * D_MODEL;         // auxk
    float* out_last = out + (size_t)2 * BATCH * D_MODEL; // num_dead

    ln_kernel<<<BATCH, 256, 0, stream>>>(x, mu, stdv, sinv);
    dead_scan_kernel<<<1, 64, 0, stream>>>(dead_mask, dead_idx, dead_cnt, num_dead, out_last);
    asplit_kernel<<<BATCH, 256, 0, stream>>>(x, mu, sinv, b_pre, Ahp, Amp);
    bsplit_kernel<<<dim3(D_MODEL / 32, D_HIDDEN / 32), 256, 0, stream>>>(w_enc, Bhp, Bmp);
    mm3_kernel<0><<<dim3(BATCH / 128, D_HIDDEN / 128), 256, 0, stream>>>(
        Ahp, Amp, Bhp, Bmp, D_MODEL, b_enc, nullptr, nullptr, p32, (long)D_HIDDEN);
    topk_kernel<<<BATCH, 256, 0, stream>>>(p32, x, mu, sinv, b_pre, w_enc, b_enc, topk_idx, topk_val);
    // Bhp/Amp/Bmp/Ahp are free from here on (encoder done; topk reads only p32/x/w_enc)
    wdec2bf_kernel<<<(int)(((size_t)D_HIDDEN * D_MODEL) / (256 * 8)), 256, 0, stream>>>(w_dec, wd16);
    decode_kernel<<<BATCH, 256, 0, stream>>>(topk_idx, topk_val, wd16, b_pre, mu, stdv, out0);
    auxg_split_kernel<<<BATCH, 256, 0, stream>>>(p32, dead_idx, dead_cnt, Ahd, Amd);
    auxb_split_kernel<<<dim3(NDEAD / 32, D_MODEL / 32), 256, 0, stream>>>(w_dec, dead_idx, Bhd, Bmd);
    mm3_kernel<1><<<dim3(BATCH / 128, D_MODEL / 128), 256, 0, stream>>>(
        Ahd, Amd, Bhd, Bmd, NDEAD, b_pre, mu, stdv, out1, (long)D_MODEL);
}

// Round 4
// 3627.330 us; speedup vs baseline: 1.1073x; 1.1073x over previous
//
#include <hip/hip_runtime.h>
#include <math.h>

#define D_MODEL  4096
#define D_HIDDEN 32768
#define BATCH    2048
#define KSEL     128
#define NDEAD    2048
#define TIECAP   192

typedef short s16x8 __attribute__((ext_vector_type(8)));
typedef float f32x4 __attribute__((ext_vector_type(4)));

// -------------------- helpers --------------------
__device__ __forceinline__ unsigned int fkey(float f) {
    unsigned int u = __float_as_uint(f);
    return (u & 0x80000000u) ? ~u : (u | 0x80000000u);
}
__device__ __forceinline__ float unfkey(unsigned int k) {
    unsigned int u = (k & 0x80000000u) ? (k & 0x7FFFFFFFu) : ~k;
    return __uint_as_float(u);
}
__device__ __forceinline__ unsigned short f2bf(float f) {  // RTNE
    unsigned int u = __float_as_uint(f);
    u += 0x7FFFu + ((u >> 16) & 1u);
    return (unsigned short)(u >> 16);
}
__device__ __forceinline__ float bf2f(unsigned short h) {
    return __uint_as_float(((unsigned int)h) << 16);
}
__device__ __forceinline__ void async_copy16(void* lds_dst, const void* gsrc) {
    __builtin_amdgcn_global_load_lds(
        (const __attribute__((address_space(1))) unsigned int*)gsrc,
        (__attribute__((address_space(3))) unsigned int*)lds_dst,
        16, 0, 0);
}

// -------------------- LayerNorm (fp64 stats) --------------------
__global__ __launch_bounds__(256) void ln_kernel(const float* __restrict__ x,
        double* __restrict__ mu, double* __restrict__ stdv, double* __restrict__ sinv)
{
    const int row = blockIdx.x;
    const int tid = threadIdx.x;
    const float* xr = x + (size_t)row * D_MODEL;
    float xv[16];
#pragma unroll
    for (int i = 0; i < 16; ++i) xv[i] = xr[tid + 256 * i];
    double s = 0.0;
#pragma unroll
    for (int i = 0; i < 16; ++i) s += (double)xv[i];
    __shared__ double red[4];
    __shared__ double sh_mu;
    const int lane = tid & 63, wid = tid >> 6;
#pragma unroll
    for (int off = 32; off > 0; off >>= 1) s += __shfl_down(s, off, 64);
    if (lane == 0) red[wid] = s;
    __syncthreads();
    if (tid == 0) sh_mu = (red[0] + red[1] + red[2] + red[3]) / (double)D_MODEL;
    __syncthreads();
    const double m = sh_mu;
    double s2 = 0.0;
#pragma unroll
    for (int i = 0; i < 16; ++i) { double d = (double)xv[i] - m; s2 += d * d; }
#pragma unroll
    for (int off = 32; off > 0; off >>= 1) s2 += __shfl_down(s2, off, 64);
    __syncthreads();
    if (lane == 0) red[wid] = s2;
    __syncthreads();
    if (tid == 0) {
        double var = (red[0] + red[1] + red[2] + red[3]) / (double)(D_MODEL - 1);
        double sd = sqrt(var);
        mu[row] = m;
        stdv[row] = sd;
        sinv[row] = 1.0 / (sd + 1e-5);
    }
}

// -------------------- dead-mask scan --------------------
__global__ void dead_scan_kernel(const unsigned char* __restrict__ mask8,
                                 int* __restrict__ dead_idx, int* __restrict__ dead_cnt,
                                 const int* __restrict__ num_dead_in, float* __restrict__ out_last)
{
    const int lane = threadIdx.x; // 64 threads, one wave
    int c = 0;
    for (int j = lane; j < D_HIDDEN; j += 64) c += (mask8[j] != 0);
#pragma unroll
    for (int off = 32; off > 0; off >>= 1) c += __shfl_down(c, off, 64);
    const int total_u8 = __shfl(c, 0, 64);
    const bool u8mode = (total_u8 == NDEAD);
    const int* mask32 = (const int*)mask8;
    int cnt = 0;
    for (int base = 0; base < D_HIDDEN; base += 64) {
        const int j = base + lane;
        const bool d = u8mode ? (mask8[j] != 0) : (mask32[j] != 0);
        const unsigned long long b = __ballot(d);
        const int pre = __popcll(b & ((1ull << lane) - 1ull));
        if (d && (cnt + pre) < NDEAD) dead_idx[cnt + pre] = j;
        cnt += __popcll(b);
    }
    const int cc = cnt > NDEAD ? NDEAD : cnt;
    if (lane == 0) {
        *dead_cnt = cc;
        *out_last = (float)(*num_dead_in);
    }
    for (int t = cc + lane; t < NDEAD; t += 64) dead_idx[t] = 0;
}

// -------------------- A split: xc -> hi bf16 plane only --------------------
__global__ __launch_bounds__(256) void asplit_kernel(
    const float* __restrict__ x, const double* __restrict__ mu, const double* __restrict__ sinv,
    const float* __restrict__ b_pre, unsigned short* __restrict__ Ahp)
{
    const int row = blockIdx.x, tid = threadIdx.x;
    const double m = mu[row], si = sinv[row];
    const float* xr = x + (size_t)row * D_MODEL;
#pragma unroll
    for (int i = 0; i < 4; ++i) {
        const int j = (i * 256 + tid) * 4;
        const float4 xv = *(const float4*)(xr + j);
        const float4 bp = *(const float4*)(b_pre + j);
        float v[4];
        v[0] = (float)(((double)xv.x - m) * si) - bp.x;
        v[1] = (float)(((double)xv.y - m) * si) - bp.y;
        v[2] = (float)(((double)xv.z - m) * si) - bp.z;
        v[3] = (float)(((double)xv.w - m) * si) - bp.w;
        uint2 hw;
        hw.x = (unsigned)f2bf(v[0]) | ((unsigned)f2bf(v[1]) << 16);
        hw.y = (unsigned)f2bf(v[2]) | ((unsigned)f2bf(v[3]) << 16);
        *(uint2*)(Ahp + (size_t)row * D_MODEL + j) = hw;
    }
}

// -------------------- B split+transpose: w_enc[k][n] -> Bh/Bm[n][k] --------------------
__global__ __launch_bounds__(256) void bsplit_kernel(
    const float* __restrict__ w_enc,
    unsigned short* __restrict__ Bhp, unsigned short* __restrict__ Bmp)
{
    __shared__ float t[32][33];
    const int bk = blockIdx.x * 32;
    const int bn = blockIdx.y * 32;
    const int tid = threadIdx.x;
    const int lr = tid >> 3, lc4 = (tid & 7) * 4;
    const float4 v = *(const float4*)(w_enc + (size_t)(bk + lr) * D_HIDDEN + bn + lc4);
    t[lr][lc4 + 0] = v.x; t[lr][lc4 + 1] = v.y; t[lr][lc4 + 2] = v.z; t[lr][lc4 + 3] = v.w;
    __syncthreads();
    float o[4];
#pragma unroll
    for (int j = 0; j < 4; ++j) o[j] = t[lc4 + j][lr];
    unsigned short h[4], md[4];
#pragma unroll
    for (int e = 0; e < 4; ++e) {
        h[e] = f2bf(o[e]);
        md[e] = f2bf(o[e] - bf2f(h[e]));
    }
    uint2 hw, mw;
    hw.x = (unsigned)h[0] | ((unsigned)h[1] << 16);
    hw.y = (unsigned)h[2] | ((unsigned)h[3] << 16);
    mw.x = (unsigned)md[0] | ((unsigned)md[1] << 16);
    mw.y = (unsigned)md[2] | ((unsigned)md[3] << 16);
    *(uint2*)(Bhp + (size_t)(bn + lr) * D_MODEL + bk + lc4) = hw;
    *(uint2*)(Bmp + (size_t)(bn + lr) * D_MODEL + bk + lc4) = mw;
}

// -------------------- w_enc transpose to fp32 [n][k] (for exact refinement) ----
__global__ __launch_bounds__(256) void wencT_kernel(
    const float* __restrict__ w_enc, float* __restrict__ wT)
{
    __shared__ float t[32][33];
    const int bk = blockIdx.x * 32;
    const int bn = blockIdx.y * 32;
    const int tid = threadIdx.x;
    const int lr = tid >> 3, lc4 = (tid & 7) * 4;
    const float4 v = *(const float4*)(w_enc + (size_t)(bk + lr) * D_HIDDEN + bn + lc4);
    t[lr][lc4 + 0] = v.x; t[lr][lc4 + 1] = v.y; t[lr][lc4 + 2] = v.z; t[lr][lc4 + 3] = v.w;
    __syncthreads();
    const int j = tid >> 3, i4 = (tid & 7) * 4;
    float4 o;
    o.x = t[i4 + 0][j]; o.y = t[i4 + 1][j]; o.z = t[i4 + 2][j]; o.w = t[i4 + 3][j];
    *(float4*)(wT + (size_t)(bn + j) * D_MODEL + bk + i4) = o;
}

// -------------------- split-bf16 MFMA GEMM (swizzled LDS) --------------------
// NPROD=2: acc = ah*bh + ah*bm       (planes Ah,Bh,Bm)
// NPROD=3: acc = ah*bh + ah*bm + am*bh  (planes Ah,Am,Bh,Bm)
// EPI=0: out = acc + bias_n[col]
// EPI=1: out = (acc + bias_n[col])*std[m] + mu[m]
template<int EPI, int NPROD>
__global__ __launch_bounds__(256) void mm3_kernel(
    const unsigned short* __restrict__ Ah, const unsigned short* __restrict__ Am,
    const unsigned short* __restrict__ Bh, const unsigned short* __restrict__ Bm,
    const int kdim, const float* __restrict__ bias_n,
    const double* __restrict__ muv, const double* __restrict__ stdvv,
    float* __restrict__ outp, const long ostride)
{
    constexpr int NPL = (NPROD == 2) ? 3 : 4;
    constexpr int SEGW = NPL * 2;           // segs per wave (NPL*8 total)
    __shared__ unsigned short lds[NPL * 128 * 32];
    const int tid = threadIdx.x;
    const int lane = tid & 63, wid = tid >> 6;
    const int m0 = blockIdx.x * 128;
    const int n0 = blockIdx.y * 128;
    const int wm = (wid >> 1) * 64, wn = (wid & 1) * 64;
    const int fr = lane & 15, kq = lane >> 4;
    const int swr = (fr >> 1) & 3;                    // read-side quad XOR
    const int qg = (lane & 3) ^ ((lane >> 3) & 3);    // write-side source quad

    f32x4 acc[4][4];
#pragma unroll
    for (int i = 0; i < 4; ++i)
#pragma unroll
        for (int j = 0; j < 4; ++j) acc[i][j] = (f32x4){0.f, 0.f, 0.f, 0.f};

    // precompute per-seg src/dst
    const unsigned short* srcs[SEGW];
    unsigned short* dsts[SEGW];
#pragma unroll
    for (int j = 0; j < SEGW; ++j) {
        const int s = wid * SEGW + j;
        const int pl = s >> 3, sr = s & 7;
        const unsigned short* gp;
        int t0;
        if (NPROD == 2) {
            gp = (pl == 0) ? Ah : (pl == 1) ? Bh : Bm;
            t0 = (pl == 0) ? m0 : n0;
        } else {
            gp = (pl == 0) ? Ah : (pl == 1) ? Am : (pl == 2) ? Bh : Bm;
            t0 = (pl < 2) ? m0 : n0;
        }
        const int r = sr * 16 + (lane >> 2);
        srcs[j] = gp + (size_t)(t0 + r) * kdim + qg * 8;
        dsts[j] = (unsigned short*)lds + pl * 4096 + sr * 512;
    }

    for (int k0 = 0; k0 < kdim; k0 += 32) {
#pragma unroll
        for (int j = 0; j < SEGW; ++j) {
            async_copy16(dsts[j], srcs[j] + k0);
        }
        __syncthreads();

        s16x8 ah[4], am[4], bh[4], bm[4];
        const int qo = (kq ^ swr) * 8;
#pragma unroll
        for (int i = 0; i < 4; ++i) {
            const int rA = wm + i * 16 + fr;
            const int rB = wn + i * 16 + fr;
            ah[i] = *(const s16x8*)(lds + 0 * 4096 + rA * 32 + qo);
            if (NPROD == 3) {
                am[i] = *(const s16x8*)(lds + 1 * 4096 + rA * 32 + qo);
                bh[i] = *(const s16x8*)(lds + 2 * 4096 + rB * 32 + qo);
                bm[i] = *(const s16x8*)(lds + 3 * 4096 + rB * 32 + qo);
            } else {
                bh[i] = *(const s16x8*)(lds + 1 * 4096 + rB * 32 + qo);
                bm[i] = *(const s16x8*)(lds + 2 * 4096 + rB * 32 + qo);
            }
        }
#pragma unroll
        for (int mi = 0; mi < 4; ++mi)
#pragma unroll
            for (int ni = 0; ni < 4; ++ni) {
                acc[mi][ni] = __builtin_amdgcn_mfma_f32_16x16x32_bf16(ah[mi], bh[ni], acc[mi][ni], 0, 0, 0);
                acc[mi][ni] = __builtin_amdgcn_mfma_f32_16x16x32_bf16(ah[mi], bm[ni], acc[mi][ni], 0, 0, 0);
                if (NPROD == 3)
                    acc[mi][ni] = __builtin_amdgcn_mfma_f32_16x16x32_bf16(am[mi], bh[ni], acc[mi][ni], 0, 0, 0);
            }
        __syncthreads();
    }
#pragma unroll
    for (int ni = 0; ni < 4; ++ni) {
        const int col = n0 + wn + ni * 16 + fr;
        const float be = bias_n[col];
#pragma unroll
        for (int mi = 0; mi < 4; ++mi) {
            const int rb = m0 + wm + mi * 16 + kq * 4;
            if (EPI == 0) {
                float* dst = outp + (size_t)rb * ostride + col;
                dst[0]                   = acc[mi][ni][0] + be;
                dst[(size_t)ostride]     = acc[mi][ni][1] + be;
                dst[2 * (size_t)ostride] = acc[mi][ni][2] + be;
                dst[3 * (size_t)ostride] = acc[mi][ni][3] + be;
            } else {
#pragma unroll
                for (int r = 0; r < 4; ++r) {
                    const int m = rb + r;
                    const float st = (float)stdvv[m];
                    const float mm = (float)muv[m];
                    outp[(size_t)m * ostride + col] = (acc[mi][ni][r] + be) * st + mm;
                }
            }
        }
    }
}

// -------------------- per-row top-128: u16-key radix + exact band refinement ----
__global__ __launch_bounds__(256) void topk_kernel(
    const float* __restrict__ p32,
    const float* __restrict__ x, const double* __restrict__ mu, const double* __restrict__ sinv,
    const float* __restrict__ b_pre, const float* __restrict__ wT, const float* __restrict__ b_enc,
    int* __restrict__ topk_idx, float* __restrict__ topk_val)
{
    const int row = blockIdx.x;
    const int tid = threadIdx.x;
    const float* pr = p32 + (size_t)row * D_HIDDEN;

    __shared__ unsigned short keys[D_HIDDEN];  // 64 KB
    __shared__ unsigned int hist[256];
    __shared__ int sh_b1, sh_k16;
    __shared__ int sh_sel, sh_tie;
    __shared__ int tie_idx[TIECAP];
    __shared__ double tie_val[TIECAP];
    __shared__ unsigned char tie_sel[TIECAP];
    __shared__ double red[256];

    // stage u16 keys (single p32 sweep)
#pragma unroll
    for (int i = 0; i < 16; ++i) {
        const int j = (i * 256 + tid) * 8;
        const float4 a = *(const float4*)(pr + j);
        const float4 b = *(const float4*)(pr + j + 4);
        uint4 w;
        w.x = (fkey(a.x) >> 16) | ((fkey(a.y) >> 16) << 16);
        w.y = (fkey(a.z) >> 16) | ((fkey(a.w) >> 16) << 16);
        w.z = (fkey(b.x) >> 16) | ((fkey(b.y) >> 16) << 16);
        w.w = (fkey(b.z) >> 16) | ((fkey(b.w) >> 16) << 16);
        *(uint4*)(keys + j) = w;
    }
    hist[tid] = 0u;
    __syncthreads();
    // pass 1: high byte
#pragma unroll
    for (int i = 0; i < 16; ++i) {
        const int j = (i * 256 + tid) * 8;
        const uint4 w = *(const uint4*)(keys + j);
        const unsigned int u[4] = {w.x, w.y, w.z, w.w};
#pragma unroll
        for (int e = 0; e < 4; ++e) {
            atomicAdd(&hist[(u[e] >> 8) & 255u], 1u);
            atomicAdd(&hist[(u[e] >> 24) & 255u], 1u);
        }
    }
    __syncthreads();
    if (tid == 0) {
        unsigned int cum = 0;
        for (int d = 255; d >= 0; --d) {
            cum += hist[d];
            if (cum >= KSEL) { sh_b1 = d; break; }
        }
    }
    __syncthreads();
    const unsigned int b1 = (unsigned int)sh_b1;
    hist[tid] = 0u;
    // count of keys with high byte > b1 must be re-derived in pass 2 scan:
    __syncthreads();
    // pass 2: low byte within bin b1; also count keys above bin
    __shared__ unsigned int sh_above;
    if (tid == 0) sh_above = 0u;
    __syncthreads();
    unsigned int my_above = 0;
#pragma unroll
    for (int i = 0; i < 16; ++i) {
        const int j = (i * 256 + tid) * 8;
        const uint4 w = *(const uint4*)(keys + j);
        const unsigned int u[4] = {w.x, w.y, w.z, w.w};
#pragma unroll
        for (int e = 0; e < 4; ++e) {
            const unsigned int k0 = u[e] & 0xFFFFu, k1 = u[e] >> 16;
            if ((k0 >> 8) == b1) atomicAdd(&hist[k0 & 255u], 1u);
            else if ((k0 >> 8) > b1) ++my_above;
            if ((k1 >> 8) == b1) atomicAdd(&hist[k1 & 255u], 1u);
            else if ((k1 >> 8) > b1) ++my_above;
        }
    }
    atomicAdd(&sh_above, my_above);
    __syncthreads();
    if (tid == 0) {
        unsigned int cum = sh_above;
        int b0 = 0;
        for (int d = 255; d >= 0; --d) {
            cum += hist[d];
            if (cum >= KSEL) { b0 = d; break; }
        }
        sh_k16 = (int)((b1 << 8) | (unsigned int)b0);
        sh_sel = 0; sh_tie = 0;
    }
    __syncthreads();
    const unsigned int K16 = (unsigned int)sh_k16;
    const float cLo = unfkey(K16 << 16);
    const float cHi = unfkey((K16 + 1u) << 16);
    const float DLT = 6e-3f;                 // >=6 sigma of 2-product enc error
    const float sureT = cHi + 2.f * DLT;
    const float candT = cLo - 2.f * DLT;
    const unsigned int sK = fkey(sureT) >> 16;   // key16 >  sK  => surely v > sureT
    const unsigned int cK = fkey(candT) >> 16;   // key16 >= cK  => candidate

    int* oidx = topk_idx + row * KSEL;
    float* oval = topk_val + row * KSEL;
#pragma unroll
    for (int i = 0; i < 16; ++i) {
        const int j0 = (i * 256 + tid) * 8;
        const uint4 w = *(const uint4*)(keys + j0);
        const unsigned int u[4] = {w.x, w.y, w.z, w.w};
#pragma unroll
        for (int e = 0; e < 8; ++e) {
            const unsigned int k = (e & 1) ? (u[e >> 1] >> 16) : (u[e >> 1] & 0xFFFFu);
            if (k < cK) continue;
            const int j = j0 + e;
            const float v = pr[j];
            if (k > sK && v > sureT) {
                const int pos = atomicAdd(&sh_sel, 1);
                oidx[pos] = j;
                oval[pos] = v > 0.f ? v : 0.f;
            } else if (v >= candT) {
                const int t = atomicAdd(&sh_tie, 1);
                if (t < TIECAP) tie_idx[t] = j;
            }
        }
    }
    __syncthreads();
    const int G = sh_sel;
    int T = sh_tie; if (T > TIECAP) T = TIECAP;
    const int R = KSEL - G;

    // exact fp64 recompute of candidates via coalesced w_encT rows
    const double m_ = mu[row], si = sinv[row];
    const float* xr = x + (size_t)row * D_MODEL;
    for (int t = 0; t < T; ++t) {
        const int col = tie_idx[t];
        const float* wr = wT + (size_t)col * D_MODEL;
        double s = 0.0;
        const int k0 = tid * 16;
#pragma unroll
        for (int q = 0; q < 4; ++q) {
            const float4 xv = *(const float4*)(xr + k0 + q * 4);
            const float4 bp = *(const float4*)(b_pre + k0 + q * 4);
            const float4 wv = *(const float4*)(wr + k0 + q * 4);
            s += (((double)xv.x - m_) * si - (double)bp.x) * (double)wv.x;
            s += (((double)xv.y - m_) * si - (double)bp.y) * (double)wv.y;
            s += (((double)xv.z - m_) * si - (double)bp.z) * (double)wv.z;
            s += (((double)xv.w - m_) * si - (double)bp.w) * (double)wv.w;
        }
        red[tid] = s;
        __syncthreads();
        for (int off = 128; off > 0; off >>= 1) {
            if (tid < off) red[tid] += red[tid + off];
            __syncthreads();
        }
        if (tid == 0) tie_val[t] = red[0] + (double)b_enc[col];
        __syncthreads();
    }
    if (tid == 0) {
        for (int t = 0; t < T; ++t) tie_sel[t] = 0;
        const int take = R < T ? R : T;
        for (int r = 0; r < take; ++r) {
            int best = -1;
            for (int t = 0; t < T; ++t) {
                if (tie_sel[t]) continue;
                if (best < 0 || tie_val[t] > tie_val[best] ||
                    (tie_val[t] == tie_val[best] && tie_idx[t] < tie_idx[best])) best = t;
            }
            tie_sel[best] = 1;
            const float ev = (float)tie_val[best];
            oidx[G + r] = tie_idx[best];
            oval[G + r] = ev > 0.f ? ev : 0.f;
        }
        for (int r = take; r < R; ++r) { oidx[G + r] = (T > 0) ? tie_idx[0] : 0; oval[G + r] = 0.f; }
    }
}

// -------------------- w_dec -> bf16 row-major copy --------------------
__global__ __launch_bounds__(256) void wdec2bf_kernel(
    const float* __restrict__ w_dec, unsigned short* __restrict__ wd16)
{
    const size_t gid = (size_t)blockIdx.x * 256 + threadIdx.x;
    const size_t base = gid * 8;
    const float4 a = *(const float4*)(w_dec + base);
    const float4 b = *(const float4*)(w_dec + base + 4);
    uint4 o;
    o.x = (unsigned)f2bf(a.x) | ((unsigned)f2bf(a.y) << 16);
    o.y = (unsigned)f2bf(a.z) | ((unsigned)f2bf(a.w) << 16);
    o.z = (unsigned)f2bf(b.x) | ((unsigned)f2bf(b.y) << 16);
    o.w = (unsigned)f2bf(b.z) | ((unsigned)f2bf(b.w) << 16);
    *(uint4*)(wd16 + base) = o;
}

// -------------------- sparse decode: recons (bf16 w_dec) --------------------
__global__ __launch_bounds__(256) void decode_kernel(
    const int* __restrict__ topk_idx, const float* __restrict__ topk_val,
    const unsigned short* __restrict__ wd16, const float* __restrict__ b_pre,
    const double* __restrict__ mu, const double* __restrict__ stdv,
    float* __restrict__ out0)
{
    const int row = blockIdx.x;
    const int tid = threadIdx.x;
    __shared__ int sidx[KSEL];
    __shared__ float sval[KSEL];
    if (tid < KSEL) {
        sidx[tid] = topk_idx[row * KSEL + tid];
        sval[tid] = topk_val[row * KSEL + tid];
    }
    __syncthreads();
    float acc[16];
#pragma unroll
    for (int i = 0; i < 16; ++i) acc[i] = 0.f;
    const int dbase = tid * 16;
    for (int k = 0; k < KSEL; ++k) {
        const float v = sval[k];
        if (v == 0.f) continue;
        const uint4* wr = (const uint4*)(wd16 + (size_t)sidx[k] * D_MODEL + dbase);
        const uint4 w0 = wr[0], w1 = wr[1];
        const unsigned int u[8] = {w0.x, w0.y, w0.z, w0.w, w1.x, w1.y, w1.z, w1.w};
#pragma unroll
        for (int i = 0; i < 8; ++i) {
            acc[2 * i]     += v * __uint_as_float(u[i] << 16);
            acc[2 * i + 1] += v * __uint_as_float(u[i] & 0xFFFF0000u);
        }
    }
    const float st = (float)stdv[row];
    const float mm = (float)mu[row];
    float* o = out0 + (size_t)row * D_MODEL + dbase;
#pragma unroll
    for (int i = 0; i < 16; ++i) {
        o[i] = (acc[i] + b_pre[dbase + i]) * st + mm;
    }
}

// -------------------- aux A gather+relu+split --------------------
__global__ __launch_bounds__(256) void auxg_split_kernel(
    const float* __restrict__ p32, const int* __restrict__ dead_idx,
    const int* __restrict__ dead_cnt,
    unsigned short* __restrict__ Ahd, unsigned short* __restrict__ Amd)
{
    const int r = blockIdx.x;
    const int tid = threadIdx.x;
    const int dc = *dead_cnt;
    for (int c = tid; c < NDEAD; c += 256) {
        float v = 0.f;
        if (c < dc) {
            v = p32[(size_t)r * D_HIDDEN + dead_idx[c]];
            v = v > 0.f ? v : 0.f;
        }
        const unsigned short h = f2bf(v);
        const unsigned short md = f2bf(v - bf2f(h));
        Ahd[(size_t)r * NDEAD + c] = h;
        Amd[(size_t)r * NDEAD + c] = md;
    }
}

// -------------------- aux B gather+transpose+split --------------------
__global__ __launch_bounds__(256) void auxb_split_kernel(
    const float* __restrict__ w_dec, const int* __restrict__ dead_idx,
    unsigned short* __restrict__ Bhd, unsigned short* __restrict__ Bmd)
{
    __shared__ float t[32][33];
    const int k0 = blockIdx.x * 32;
    const int n0 = blockIdx.y * 32;
    const int tid = threadIdx.x;
    const int i = tid >> 3, j4 = (tid & 7) * 4;
    const int srow = dead_idx[k0 + i];
    const float4 v = *(const float4*)(w_dec + (size_t)srow * D_MODEL + n0 + j4);
    t[i][j4 + 0] = v.x; t[i][j4 + 1] = v.y; t[i][j4 + 2] = v.z; t[i][j4 + 3] = v.w;
    __syncthreads();
    const int j = tid >> 3, i4 = (tid & 7) * 4;
    unsigned short h[4], md[4];
#pragma unroll
    for (int e = 0; e < 4; ++e) {
        const float vv = t[i4 + e][j];
        h[e] = f2bf(vv);
        md[e] = f2bf(vv - bf2f(h[e]));
    }
    uint2 hw, mw;
    hw.x = (unsigned)h[0] | ((unsigned)h[1] << 16);
    hw.y = (unsigned)h[2] | ((unsigned)h[3] << 16);
    mw.x = (unsigned)md[0] | ((unsigned)md[1] << 16);
    mw.y = (unsigned)md[2] | ((unsigned)md[3] << 16);
    *(uint2*)(Bhd + (size_t)(n0 + j) * NDEAD + k0 + i4) = hw;
    *(uint2*)(Bmd + (size_t)(n0 + j) * NDEAD + k0 + i4) = mw;
}

// -------------------- launch --------------------
extern "C" void kernel_launch(void* const* d_in, const int* in_sizes, int n_in,
                              void* d_out, int out_size, void* d_ws, size_t ws_size,
                              hipStream_t stream)
{
    (void)in_sizes; (void)n_in; (void)out_size; (void)ws_size;
    const float* x      = (const float*)d_in[0];
    const float* w_enc  = (const float*)d_in[1];
    const float* w_dec  = (const float*)d_in[2];
    const float* b_enc  = (const float*)d_in[3];
    const float* b_pre  = (const float*)d_in[4];
    const unsigned char* dead_mask = (const unsigned char*)d_in[5];
    const int* num_dead = (const int*)d_in[6];
    float* out = (float*)d_out;

    char* base = (char*)d_ws;
    char* w = base;
    auto alloc = [&](size_t bytes) -> char* {
        char* p = w;
        w += (bytes + 255) & ~(size_t)255;
        return p;
    };
    float* p32       = (float*)alloc((size_t)BATCH * D_HIDDEN * 4);   // 256 MB
    double* mu       = (double*)alloc((size_t)BATCH * 8);
    double* stdv     = (double*)alloc((size_t)BATCH * 8);
    double* sinv     = (double*)alloc((size_t)BATCH * 8);
    int* topk_idx    = (int*)alloc((size_t)BATCH * KSEL * 4);
    float* topk_val  = (float*)alloc((size_t)BATCH * KSEL * 4);
    int* dead_idx    = (int*)alloc((size_t)NDEAD * 4);
    int* dead_cnt    = (int*)alloc(256);
    unsigned short* Ahp = (unsigned short*)alloc((size_t)BATCH * D_MODEL * 2);    // 16 MB
    unsigned short* Bhp = (unsigned short*)alloc((size_t)D_HIDDEN * D_MODEL * 2); // 256 MB
    unsigned short* Bmp = (unsigned short*)alloc((size_t)D_HIDDEN * D_MODEL * 2); // 256 MB (contiguous after Bhp)

    // time-multiplexed aliases:
    float* wT   = (float*)Bhp;                           // 512 MB fp32 w_encT (Bhp+Bmp), built AFTER enc
    unsigned short* wd16 = Bhp;                          // 256 MB bf16 w_dec, built AFTER topk
    unsigned short* Ahd  = Ahp;                          // 8 MB
    unsigned short* Amd  = Ahp + (size_t)BATCH * NDEAD;  // 8 MB
    unsigned short* Bhd  = Bmp;                          // 16 MB (after topk)
    unsigned short* Bmd  = Bmp + (size_t)D_MODEL * NDEAD;// 16 MB

    float* out0 = out;                                   // recons
    float* out1 = out + (size_t)BATCH * D_MODEL;         // auxk
    float* out_last = out + (size_t)2 * BATCH * D_MODEL; // num_dead

    ln_kernel<<<BATCH, 256, 0, stream>>>(x, mu, stdv, sinv);
    dead_scan_kernel<<<1, 64, 0, stream>>>(dead_mask, dead_idx, dead_cnt, num_dead, out_last);
    asplit_kernel<<<BATCH, 256, 0, stream>>>(x, mu, sinv, b_pre, Ahp);
    bsplit_kernel<<<dim3(D_MODEL / 32, D_HIDDEN / 32), 256, 0, stream>>>(w_enc, Bhp, Bmp);
    mm3_kernel<0, 2><<<dim3(BATCH / 128, D_HIDDEN / 128), 256, 0, stream>>>(
        Ahp, nullptr, Bhp, Bmp, D_MODEL, b_enc, nullptr, nullptr, p32, (long)D_HIDDEN);
    wencT_kernel<<<dim3(D_MODEL / 32, D_HIDDEN / 32), 256, 0, stream>>>(w_enc, wT);
    topk_kernel<<<BATCH, 256, 0, stream>>>(p32, x, mu, sinv, b_pre, wT, b_enc, topk_idx, topk_val);
    auxg_split_kernel<<<BATCH, 256, 0, stream>>>(p32, dead_idx, dead_cnt, Ahd, Amd);
    auxb_split_kernel<<<dim3(NDEAD / 32, D_MODEL / 32), 256, 0, stream>>>(w_dec, dead_idx, Bhd, Bmd);
    wdec2bf_kernel<<<(int)(((size_t)D_HIDDEN * D_MODEL) / (256 * 8)), 256, 0, stream>>>(w_dec, wd16);
    decode_kernel<<<BATCH, 256, 0, stream>>>(topk_idx, topk_val, wd16, b_pre, mu, stdv, out0);
    mm3_kernel<1, 3><<<dim3(BATCH / 128, D_MODEL / 128), 256, 0, stream>>>(
        Ahd, Amd, Bhd, Bmd, NDEAD, b_pre, mu, stdv, out1, (long)D_MODEL);
}

// Round 5
// 3117.897 us; speedup vs baseline: 1.2882x; 1.1634x over previous
//
#include <hip/hip_runtime.h>
#include <math.h>

#define D_MODEL  4096
#define D_HIDDEN 32768
#define BATCH    2048
#define KSEL     128
#define NDEAD    2048
#define TIECAP   256

typedef short s16x8 __attribute__((ext_vector_type(8)));
typedef float f32x4 __attribute__((ext_vector_type(4)));

// -------------------- helpers --------------------
__device__ __forceinline__ unsigned int fkey(float f) {
    unsigned int u = __float_as_uint(f);
    return (u & 0x80000000u) ? ~u : (u | 0x80000000u);
}
__device__ __forceinline__ unsigned short f2bf(float f) {  // RTNE
    unsigned int u = __float_as_uint(f);
    u += 0x7FFFu + ((u >> 16) & 1u);
    return (unsigned short)(u >> 16);
}
__device__ __forceinline__ float bf2f(unsigned short h) {
    return __uint_as_float(((unsigned int)h) << 16);
}
// per-16-bit-lane order-preserving key transform (packed pair)
__device__ __forceinline__ unsigned int key16x2(unsigned int u) {
    const unsigned int s = (u >> 15) & 0x10001u;
    const unsigned int mask = s * 0xFFFFu;
    return (u ^ mask) | (~mask & 0x80008000u);
}
__device__ __forceinline__ float unkey16(unsigned int k) {  // 16-bit key -> float
    const unsigned int u = (k & 0x8000u) ? (k & 0x7FFFu) : (~k & 0xFFFFu);
    return __uint_as_float(u << 16);
}
__device__ __forceinline__ void async_copy16(void* lds_dst, const void* gsrc) {
    __builtin_amdgcn_global_load_lds(
        (const __attribute__((address_space(1))) unsigned int*)gsrc,
        (__attribute__((address_space(3))) unsigned int*)lds_dst,
        16, 0, 0);
}

// -------------------- LayerNorm (fp64 stats) --------------------
__global__ __launch_bounds__(256) void ln_kernel(const float* __restrict__ x,
        double* __restrict__ mu, double* __restrict__ stdv, double* __restrict__ sinv)
{
    const int row = blockIdx.x;
    const int tid = threadIdx.x;
    const float* xr = x + (size_t)row * D_MODEL;
    float xv[16];
#pragma unroll
    for (int i = 0; i < 16; ++i) xv[i] = xr[tid + 256 * i];
    double s = 0.0;
#pragma unroll
    for (int i = 0; i < 16; ++i) s += (double)xv[i];
    __shared__ double red[4];
    __shared__ double sh_mu;
    const int lane = tid & 63, wid = tid >> 6;
#pragma unroll
    for (int off = 32; off > 0; off >>= 1) s += __shfl_down(s, off, 64);
    if (lane == 0) red[wid] = s;
    __syncthreads();
    if (tid == 0) sh_mu = (red[0] + red[1] + red[2] + red[3]) / (double)D_MODEL;
    __syncthreads();
    const double m = sh_mu;
    double s2 = 0.0;
#pragma unroll
    for (int i = 0; i < 16; ++i) { double d = (double)xv[i] - m; s2 += d * d; }
#pragma unroll
    for (int off = 32; off > 0; off >>= 1) s2 += __shfl_down(s2, off, 64);
    __syncthreads();
    if (lane == 0) red[wid] = s2;
    __syncthreads();
    if (tid == 0) {
        double var = (red[0] + red[1] + red[2] + red[3]) / (double)(D_MODEL - 1);
        double sd = sqrt(var);
        mu[row] = m;
        stdv[row] = sd;
        sinv[row] = 1.0 / (sd + 1e-5);
    }
}

// -------------------- dead-mask scan --------------------
__global__ void dead_scan_kernel(const unsigned char* __restrict__ mask8,
                                 int* __restrict__ dead_idx, int* __restrict__ dead_cnt,
                                 const int* __restrict__ num_dead_in, float* __restrict__ out_last)
{
    const int lane = threadIdx.x; // 64 threads, one wave
    int c = 0;
    for (int j = lane; j < D_HIDDEN; j += 64) c += (mask8[j] != 0);
#pragma unroll
    for (int off = 32; off > 0; off >>= 1) c += __shfl_down(c, off, 64);
    const int total_u8 = __shfl(c, 0, 64);
    const bool u8mode = (total_u8 == NDEAD);
    const int* mask32 = (const int*)mask8;
    int cnt = 0;
    for (int base = 0; base < D_HIDDEN; base += 64) {
        const int j = base + lane;
        const bool d = u8mode ? (mask8[j] != 0) : (mask32[j] != 0);
        const unsigned long long b = __ballot(d);
        const int pre = __popcll(b & ((1ull << lane) - 1ull));
        if (d && (cnt + pre) < NDEAD) dead_idx[cnt + pre] = j;
        cnt += __popcll(b);
    }
    const int cc = cnt > NDEAD ? NDEAD : cnt;
    if (lane == 0) {
        *dead_cnt = cc;
        *out_last = (float)(*num_dead_in);
    }
    for (int t = cc + lane; t < NDEAD; t += 64) dead_idx[t] = 0;
}

// -------------------- A: xc -> bf16 --------------------
__global__ __launch_bounds__(256) void asplit_kernel(
    const float* __restrict__ x, const double* __restrict__ mu, const double* __restrict__ sinv,
    const float* __restrict__ b_pre, unsigned short* __restrict__ Ahp)
{
    const int row = blockIdx.x, tid = threadIdx.x;
    const double m = mu[row], si = sinv[row];
    const float* xr = x + (size_t)row * D_MODEL;
#pragma unroll
    for (int i = 0; i < 4; ++i) {
        const int j = (i * 256 + tid) * 4;
        const float4 xv = *(const float4*)(xr + j);
        const float4 bp = *(const float4*)(b_pre + j);
        float v[4];
        v[0] = (float)(((double)xv.x - m) * si) - bp.x;
        v[1] = (float)(((double)xv.y - m) * si) - bp.y;
        v[2] = (float)(((double)xv.z - m) * si) - bp.z;
        v[3] = (float)(((double)xv.w - m) * si) - bp.w;
        uint2 hw;
        hw.x = (unsigned)f2bf(v[0]) | ((unsigned)f2bf(v[1]) << 16);
        hw.y = (unsigned)f2bf(v[2]) | ((unsigned)f2bf(v[3]) << 16);
        *(uint2*)(Ahp + (size_t)row * D_MODEL + j) = hw;
    }
}

// -------------------- B: w_enc[k][n] -> Bh[n][k] bf16 --------------------
__global__ __launch_bounds__(256) void bsplit_kernel(
    const float* __restrict__ w_enc, unsigned short* __restrict__ Bhp)
{
    __shared__ float t[32][33];
    const int bk = blockIdx.x * 32;
    const int bn = blockIdx.y * 32;
    const int tid = threadIdx.x;
    const int lr = tid >> 3, lc4 = (tid & 7) * 4;
    const float4 v = *(const float4*)(w_enc + (size_t)(bk + lr) * D_HIDDEN + bn + lc4);
    t[lr][lc4 + 0] = v.x; t[lr][lc4 + 1] = v.y; t[lr][lc4 + 2] = v.z; t[lr][lc4 + 3] = v.w;
    __syncthreads();
    float o[4];
#pragma unroll
    for (int j = 0; j < 4; ++j) o[j] = t[lc4 + j][lr];
    uint2 hw;
    hw.x = (unsigned)f2bf(o[0]) | ((unsigned)f2bf(o[1]) << 16);
    hw.y = (unsigned)f2bf(o[2]) | ((unsigned)f2bf(o[3]) << 16);
    *(uint2*)(Bhp + (size_t)(bn + lr) * D_MODEL + bk + lc4) = hw;
}

// -------------------- w_enc transpose to fp32 [n][k] --------------------
__global__ __launch_bounds__(256) void wencT_kernel(
    const float* __restrict__ w_enc, float* __restrict__ wT)
{
    __shared__ float t[32][33];
    const int bk = blockIdx.x * 32;
    const int bn = blockIdx.y * 32;
    const int tid = threadIdx.x;
    const int lr = tid >> 3, lc4 = (tid & 7) * 4;
    const float4 v = *(const float4*)(w_enc + (size_t)(bk + lr) * D_HIDDEN + bn + lc4);
    t[lr][lc4 + 0] = v.x; t[lr][lc4 + 1] = v.y; t[lr][lc4 + 2] = v.z; t[lr][lc4 + 3] = v.w;
    __syncthreads();
    const int j = tid >> 3, i4 = (tid & 7) * 4;
    float4 o;
    o.x = t[i4 + 0][j]; o.y = t[i4 + 1][j]; o.z = t[i4 + 2][j]; o.w = t[i4 + 3][j];
    *(float4*)(wT + (size_t)(bn + j) * D_MODEL + bk + i4) = o;
}

// -------------------- bf16 MFMA GEMM: 128x128 tile, BK=32, LDS dbuf ---------
// A[m][k], B[n][k] bf16 (B^T layout). out[m][n].
// EPI=0: bf16 out = bf16(acc + bias_n[col])            (encoder -> p16)
// EPI=1: fp32 out = (acc + bias_n[col])*std[m] + mu[m] (aux -> out1)
template<int EPI>
__global__ __launch_bounds__(256) void mm_kernel(
    const unsigned short* __restrict__ A, const unsigned short* __restrict__ B,
    const int kdim, const int ntiles_x,
    const float* __restrict__ bias_n,
    const double* __restrict__ muv, const double* __restrict__ stdvv,
    void* __restrict__ outp, const long ostride)
{
    __shared__ unsigned short lds[2 * 2 * 128 * 32];  // [buf][plane A/B][row][32]
    const int tid = threadIdx.x;
    const int lane = tid & 63, wid = tid >> 6;
    // XCD-aware block swizzle (gridDim.x % 8 == 0)
    const int cpx = gridDim.x >> 3;
    const int orig = blockIdx.x;
    const int wg = (orig & 7) * cpx + (orig >> 3);
    const int m0 = (wg % ntiles_x) * 128;
    const int n0 = (wg / ntiles_x) * 128;
    const int wm = (wid >> 1) * 64, wn = (wid & 1) * 64;
    const int fr = lane & 15, kq = lane >> 4;
    const int swr = (fr >> 1) & 3;                    // read-side quad XOR
    const int qg = (lane & 3) ^ ((lane >> 3) & 3);    // write-side source quad
    const int qo = (kq ^ swr) * 8;

    f32x4 acc[4][4];
#pragma unroll
    for (int i = 0; i < 4; ++i)
#pragma unroll
        for (int j = 0; j < 4; ++j) acc[i][j] = (f32x4){0.f, 0.f, 0.f, 0.f};

    // 16 staging segs (A:8, B:8), 4 per wave; each seg = 16 rows x 32 cols bf16 = 1KB
    const unsigned short* srcs[4];
    int d0[4];
#pragma unroll
    for (int j = 0; j < 4; ++j) {
        const int s = wid * 4 + j;
        const int pl = s >> 3, sr = s & 7;
        const int r = sr * 16 + (lane >> 2);
        srcs[j] = (pl ? B : A) + (size_t)((pl ? n0 : m0) + r) * kdim + qg * 8;
        d0[j] = pl * 4096 + sr * 512;
    }

    const int NT = kdim >> 5;
    // prologue: stage tile 0 into buf 0
#pragma unroll
    for (int j = 0; j < 4; ++j) async_copy16(lds + d0[j], srcs[j]);
    __syncthreads();

    for (int t = 0; t < NT; ++t) {
        const int cur = t & 1;
        if (t + 1 < NT) {
            const int k1 = (t + 1) << 5;
            const int boff = (cur ^ 1) * 8192;
#pragma unroll
            for (int j = 0; j < 4; ++j) async_copy16(lds + boff + d0[j], srcs[j] + k1);
        }
        const unsigned short* la = lds + cur * 8192;
        const unsigned short* lb = la + 4096;
        s16x8 a[4], b[4];
#pragma unroll
        for (int i = 0; i < 4; ++i) {
            a[i] = *(const s16x8*)(la + (wm + i * 16 + fr) * 32 + qo);
            b[i] = *(const s16x8*)(lb + (wn + i * 16 + fr) * 32 + qo);
        }
#pragma unroll
        for (int mi = 0; mi < 4; ++mi)
#pragma unroll
            for (int ni = 0; ni < 4; ++ni)
                acc[mi][ni] = __builtin_amdgcn_mfma_f32_16x16x32_bf16(a[mi], b[ni], acc[mi][ni], 0, 0, 0);
        __syncthreads();
    }

#pragma unroll
    for (int ni = 0; ni < 4; ++ni) {
        const int col = n0 + wn + ni * 16 + fr;
        const float be = bias_n[col];
#pragma unroll
        for (int mi = 0; mi < 4; ++mi) {
            const int rb = m0 + wm + mi * 16 + kq * 4;
            if (EPI == 0) {
                unsigned short* O = (unsigned short*)outp;
#pragma unroll
                for (int r = 0; r < 4; ++r)
                    O[(size_t)(rb + r) * ostride + col] = f2bf(acc[mi][ni][r] + be);
            } else {
                float* O = (float*)outp;
#pragma unroll
                for (int r = 0; r < 4; ++r) {
                    const int m = rb + r;
                    O[(size_t)m * ostride + col] =
                        (acc[mi][ni][r] + be) * (float)stdvv[m] + (float)muv[m];
                }
            }
        }
    }
}

// -------------------- per-row top-128 on bf16 keys + exact fp64 band refine ----
__global__ __launch_bounds__(256) void topk_kernel(
    const unsigned short* __restrict__ p16,
    const float* __restrict__ x, const double* __restrict__ mu, const double* __restrict__ sinv,
    const float* __restrict__ b_pre, const float* __restrict__ wT, const float* __restrict__ b_enc,
    int* __restrict__ topk_idx, float* __restrict__ topk_val)
{
    const int row = blockIdx.x;
    const int tid = threadIdx.x;
    const int lane = tid & 63, wv = tid >> 6;
    const unsigned short* pr = p16 + (size_t)row * D_HIDDEN;

    __shared__ unsigned short keys[D_HIDDEN];   // 64 KB (order-preserving u16 keys)
    __shared__ unsigned int hist[256];
    __shared__ int sh_b1, sh_k16;
    __shared__ unsigned int sh_above;
    __shared__ int sh_sel, sh_tie;
    __shared__ int tie_idx[TIECAP];
    __shared__ double tie_val[TIECAP];
    __shared__ unsigned char tie_sel[TIECAP];

    // stage transformed keys (single global sweep of p16)
#pragma unroll
    for (int i = 0; i < 16; ++i) {
        const int j = (i * 256 + tid) * 8;
        uint4 w = *(const uint4*)(pr + j);
        w.x = key16x2(w.x); w.y = key16x2(w.y); w.z = key16x2(w.z); w.w = key16x2(w.w);
        *(uint4*)(keys + j) = w;
    }
    hist[tid] = 0u;
    __syncthreads();
    // pass 1: high byte of key16
#pragma unroll
    for (int i = 0; i < 16; ++i) {
        const int j = (i * 256 + tid) * 8;
        const uint4 w = *(const uint4*)(keys + j);
        const unsigned int u[4] = {w.x, w.y, w.z, w.w};
#pragma unroll
        for (int e = 0; e < 4; ++e) {
            atomicAdd(&hist[(u[e] >> 8) & 255u], 1u);
            atomicAdd(&hist[(u[e] >> 24) & 255u], 1u);
        }
    }
    __syncthreads();
    if (tid == 0) {
        unsigned int cum = 0;
        for (int d = 255; d >= 0; --d) {
            cum += hist[d];
            if (cum >= KSEL) { sh_b1 = d; break; }
        }
        sh_above = 0u;
    }
    __syncthreads();
    const unsigned int b1 = (unsigned int)sh_b1;
    hist[tid] = 0u;
    __syncthreads();
    // pass 2: low byte within bin b1 + count above
    unsigned int my_above = 0;
#pragma unroll
    for (int i = 0; i < 16; ++i) {
        const int j = (i * 256 + tid) * 8;
        const uint4 w = *(const uint4*)(keys + j);
        const unsigned int u[4] = {w.x, w.y, w.z, w.w};
#pragma unroll
        for (int e = 0; e < 4; ++e) {
            const unsigned int k0 = u[e] & 0xFFFFu, k1 = u[e] >> 16;
            if ((k0 >> 8) == b1) atomicAdd(&hist[k0 & 255u], 1u);
            else if ((k0 >> 8) > b1) ++my_above;
            if ((k1 >> 8) == b1) atomicAdd(&hist[k1 & 255u], 1u);
            else if ((k1 >> 8) > b1) ++my_above;
        }
    }
    atomicAdd(&sh_above, my_above);
    __syncthreads();
    if (tid == 0) {
        unsigned int cum = sh_above;
        int b0 = 0;
        for (int d = 255; d >= 0; --d) {
            cum += hist[d];
            if (cum >= KSEL) { b0 = d; break; }
        }
        sh_k16 = (int)((b1 << 8) | (unsigned int)b0);
        sh_sel = 0; sh_tie = 0;
    }
    __syncthreads();
    const unsigned int K16 = (unsigned int)sh_k16;
    const float vc = unkey16(K16);           // approx rank-128 value (bf16 grid)
    const float DLT = 1.3e-2f;               // bounds |p16 - exact| near cutoff
    const float sureT = vc + 2.f * DLT;
    const float candT = vc - 2.f * DLT;
    const unsigned int sK = fkey(sureT) >> 16;
    const unsigned int cK = fkey(candT) >> 16;

    int* oidx = topk_idx + row * KSEL;
    float* oval = topk_val + row * KSEL;
#pragma unroll
    for (int i = 0; i < 16; ++i) {
        const int j0 = (i * 256 + tid) * 8;
        const uint4 w = *(const uint4*)(keys + j0);
        const unsigned int u[4] = {w.x, w.y, w.z, w.w};
#pragma unroll
        for (int e = 0; e < 8; ++e) {
            const unsigned int k = (e & 1) ? (u[e >> 1] >> 16) : (u[e >> 1] & 0xFFFFu);
            if (k < cK) continue;
            const float v = unkey16(k);
            if (k > sK && v > sureT) {
                const int pos = atomicAdd(&sh_sel, 1);
                oidx[pos] = j0 + e;
                oval[pos] = v > 0.f ? v : 0.f;
            } else if (v >= candT) {
                const int t = atomicAdd(&sh_tie, 1);
                if (t < TIECAP) tie_idx[t] = j0 + e;
            }
        }
    }
    __syncthreads();
    const int G = sh_sel;
    int T = sh_tie; if (T > TIECAP) T = TIECAP;
    const int R = KSEL - G;

    // exact fp64 recompute of candidates, wave-parallel, coalesced wT rows
    const double m_ = mu[row], si = sinv[row];
    const float* xr = x + (size_t)row * D_MODEL;
    for (int t = wv; t < T; t += 4) {
        const int col = tie_idx[t];
        const float* wr = wT + (size_t)col * D_MODEL;
        double s = 0.0;
        for (int k = lane * 4; k < D_MODEL; k += 256) {
            const float4 xv = *(const float4*)(xr + k);
            const float4 bp = *(const float4*)(b_pre + k);
            const float4 wv4 = *(const float4*)(wr + k);
            s += (((double)xv.x - m_) * si - (double)bp.x) * (double)wv4.x;
            s += (((double)xv.y - m_) * si - (double)bp.y) * (double)wv4.y;
            s += (((double)xv.z - m_) * si - (double)bp.z) * (double)wv4.z;
            s += (((double)xv.w - m_) * si - (double)bp.w) * (double)wv4.w;
        }
#pragma unroll
        for (int off = 32; off > 0; off >>= 1) s += __shfl_down(s, off, 64);
        if (lane == 0) tie_val[t] = s + (double)b_enc[col];
    }
    __syncthreads();
    if (tid == 0) {
        for (int t = 0; t < T; ++t) tie_sel[t] = 0;
        const int take = R < T ? R : T;
        for (int r = 0; r < take; ++r) {
            int best = -1;
            for (int t = 0; t < T; ++t) {
                if (tie_sel[t]) continue;
                if (best < 0 || tie_val[t] > tie_val[best] ||
                    (tie_val[t] == tie_val[best] && tie_idx[t] < tie_idx[best])) best = t;
            }
            tie_sel[best] = 1;
            const float ev = (float)tie_val[best];
            oidx[G + r] = tie_idx[best];
            oval[G + r] = ev > 0.f ? ev : 0.f;
        }
        for (int r = take; r < R; ++r) { oidx[G + r] = (T > 0) ? tie_idx[0] : 0; oval[G + r] = 0.f; }
    }
}

// -------------------- w_dec -> bf16 row-major copy --------------------
__global__ __launch_bounds__(256) void wdec2bf_kernel(
    const float* __restrict__ w_dec, unsigned short* __restrict__ wd16)
{
    const size_t gid = (size_t)blockIdx.x * 256 + threadIdx.x;
    const size_t base = gid * 8;
    const float4 a = *(const float4*)(w_dec + base);
    const float4 b = *(const float4*)(w_dec + base + 4);
    uint4 o;
    o.x = (unsigned)f2bf(a.x) | ((unsigned)f2bf(a.y) << 16);
    o.y = (unsigned)f2bf(a.z) | ((unsigned)f2bf(a.w) << 16);
    o.z = (unsigned)f2bf(b.x) | ((unsigned)f2bf(b.y) << 16);
    o.w = (unsigned)f2bf(b.z) | ((unsigned)f2bf(b.w) << 16);
    *(uint4*)(wd16 + base) = o;
}

// -------------------- sparse decode: recons (bf16 w_dec) --------------------
__global__ __launch_bounds__(256) void decode_kernel(
    const int* __restrict__ topk_idx, const float* __restrict__ topk_val,
    const unsigned short* __restrict__ wd16, const float* __restrict__ b_pre,
    const double* __restrict__ mu, const double* __restrict__ stdv,
    float* __restrict__ out0)
{
    const int row = blockIdx.x;
    const int tid = threadIdx.x;
    __shared__ int sidx[KSEL];
    __shared__ float sval[KSEL];
    if (tid < KSEL) {
        sidx[tid] = topk_idx[row * KSEL + tid];
        sval[tid] = topk_val[row * KSEL + tid];
    }
    __syncthreads();
    float acc[16];
#pragma unroll
    for (int i = 0; i < 16; ++i) acc[i] = 0.f;
    const int dbase = tid * 16;
    for (int k = 0; k < KSEL; ++k) {
        const float v = sval[k];
        if (v == 0.f) continue;
        const uint4* wr = (const uint4*)(wd16 + (size_t)sidx[k] * D_MODEL + dbase);
        const uint4 w0 = wr[0], w1 = wr[1];
        const unsigned int u[8] = {w0.x, w0.y, w0.z, w0.w, w1.x, w1.y, w1.z, w1.w};
#pragma unroll
        for (int i = 0; i < 8; ++i) {
            acc[2 * i]     += v * __uint_as_float(u[i] << 16);
            acc[2 * i + 1] += v * __uint_as_float(u[i] & 0xFFFF0000u);
        }
    }
    const float st = (float)stdv[row];
    const float mm = (float)mu[row];
    float* o = out0 + (size_t)row * D_MODEL + dbase;
#pragma unroll
    for (int i = 0; i < 16; ++i) {
        o[i] = (acc[i] + b_pre[dbase + i]) * st + mm;
    }
}

// -------------------- aux A gather+relu (bf16 passthrough) --------------------
__global__ __launch_bounds__(256) void auxg_kernel(
    const unsigned short* __restrict__ p16, const int* __restrict__ dead_idx,
    const int* __restrict__ dead_cnt, unsigned short* __restrict__ Ahd)
{
    const int r = blockIdx.x;
    const int tid = threadIdx.x;
    const int dc = *dead_cnt;
#pragma unroll
    for (int i = 0; i < 8; ++i) {
        const int c = i * 256 + tid;
        unsigned short v = 0;
        if (c < dc) {
            const unsigned short u = p16[(size_t)r * D_HIDDEN + dead_idx[c]];
            v = (u & 0x8000u) ? (unsigned short)0 : u;   // relu on bf16 bits
        }
        Ahd[(size_t)r * NDEAD + c] = v;
    }
}

// -------------------- aux B gather+transpose (bf16) --------------------
__global__ __launch_bounds__(256) void auxb_kernel(
    const float* __restrict__ w_dec, const int* __restrict__ dead_idx,
    unsigned short* __restrict__ Bhd)
{
    __shared__ float t[32][33];
    const int k0 = blockIdx.x * 32;
    const int n0 = blockIdx.y * 32;
    const int tid = threadIdx.x;
    const int i = tid >> 3, j4 = (tid & 7) * 4;
    const int srow = dead_idx[k0 + i];
    const float4 v = *(const float4*)(w_dec + (size_t)srow * D_MODEL + n0 + j4);
    t[i][j4 + 0] = v.x; t[i][j4 + 1] = v.y; t[i][j4 + 2] = v.z; t[i][j4 + 3] = v.w;
    __syncthreads();
    const int j = tid >> 3, i4 = (tid & 7) * 4;
    uint2 hw;
    hw.x = (unsigned)f2bf(t[i4 + 0][j]) | ((unsigned)f2bf(t[i4 + 1][j]) << 16);
    hw.y = (unsigned)f2bf(t[i4 + 2][j]) | ((unsigned)f2bf(t[i4 + 3][j]) << 16);
    *(uint2*)(Bhd + (size_t)(n0 + j) * NDEAD + k0 + i4) = hw;
}

// -------------------- launch --------------------
extern "C" void kernel_launch(void* const* d_in, const int* in_sizes, int n_in,
                              void* d_out, int out_size, void* d_ws, size_t ws_size,
                              hipStream_t stream)
{
    (void)in_sizes; (void)n_in; (void)out_size; (void)ws_size;
    const float* x      = (const float*)d_in[0];
    const float* w_enc  = (const float*)d_in[1];
    const float* w_dec  = (const float*)d_in[2];
    const float* b_enc  = (const float*)d_in[3];
    const float* b_pre  = (const float*)d_in[4];
    const unsigned char* dead_mask = (const unsigned char*)d_in[5];
    const int* num_dead = (const int*)d_in[6];
    float* out = (float*)d_out;

    char* base = (char*)d_ws;
    char* w = base;
    auto alloc = [&](size_t bytes) -> char* {
        char* p = w;
        w += (bytes + 255) & ~(size_t)255;
        return p;
    };
    unsigned short* p16 = (unsigned short*)alloc((size_t)BATCH * D_HIDDEN * 2); // 128 MB
    double* mu       = (double*)alloc((size_t)BATCH * 8);
    double* stdv     = (double*)alloc((size_t)BATCH * 8);
    double* sinv     = (double*)alloc((size_t)BATCH * 8);
    int* topk_idx    = (int*)alloc((size_t)BATCH * KSEL * 4);
    float* topk_val  = (float*)alloc((size_t)BATCH * KSEL * 4);
    int* dead_idx    = (int*)alloc((size_t)NDEAD * 4);
    int* dead_cnt    = (int*)alloc(256);
    unsigned short* Ahp = (unsigned short*)alloc((size_t)BATCH * D_MODEL * 2);    // 16 MB
    char* region     = alloc((size_t)D_HIDDEN * D_MODEL * 4);                     // 512 MB

    // time-multiplexed region:
    unsigned short* Bhp = (unsigned short*)region;                 // 256 MB, enc phase
    float* wT   = (float*)region;                                  // 512 MB, topk phase
    unsigned short* wd16 = (unsigned short*)region;                // 256 MB, decode phase
    unsigned short* Bhd  = (unsigned short*)(region + (size_t)D_HIDDEN * D_MODEL * 2); // 16 MB
    unsigned short* Ahd  = Ahp;                                    // 8 MB (Ahp dead after enc)

    float* out0 = out;                                   // recons
    float* out1 = out + (size_t)BATCH * D_MODEL;         // auxk
    float* out_last = out + (size_t)2 * BATCH * D_MODEL; // num_dead

    ln_kernel<<<BATCH, 256, 0, stream>>>(x, mu, stdv, sinv);
    dead_scan_kernel<<<1, 64, 0, stream>>>(dead_mask, dead_idx, dead_cnt, num_dead, out_last);
    asplit_kernel<<<BATCH, 256, 0, stream>>>(x, mu, sinv, b_pre, Ahp);
    bsplit_kernel<<<dim3(D_MODEL / 32, D_HIDDEN / 32), 256, 0, stream>>>(w_enc, Bhp);
    mm_kernel<0><<<(BATCH / 128) * (D_HIDDEN / 128), 256, 0, stream>>>(
        Ahp, Bhp, D_MODEL, BATCH / 128, b_enc, nullptr, nullptr, p16, (long)D_HIDDEN);
    wencT_kernel<<<dim3(D_MODEL / 32, D_HIDDEN / 32), 256, 0, stream>>>(w_enc, wT);
    topk_kernel<<<BATCH, 256, 0, stream>>>(p16, x, mu, sinv, b_pre, wT, b_enc, topk_idx, topk_val);
    auxg_kernel<<<BATCH, 256, 0, stream>>>(p16, dead_idx, dead_cnt, Ahd);
    auxb_kernel<<<dim3(NDEAD / 32, D_MODEL / 32), 256, 0, stream>>>(w_dec, dead_idx, Bhd);
    wdec2bf_kernel<<<(int)(((size_t)D_HIDDEN * D_MODEL) / (256 * 8)), 256, 0, stream>>>(w_dec, wd16);
    decode_kernel<<<BATCH, 256, 0, stream>>>(topk_idx, topk_val, wd16, b_pre, mu, stdv, out0);
    mm_kernel<1><<<(BATCH / 128) * (D_MODEL / 128), 256, 0, stream>>>(
        Ahd, Bhd, NDEAD, BATCH / 128, b_pre, mu, stdv, out1, (long)D_MODEL);
}